// Round 4
// baseline (101.397 us; speedup 1.0000x reference)
//
#include <hip/hip_runtime.h>
#include <math.h>

// ImpulseSolverLCP — wave-per-batch register LU, fp32, rolled-chunked edition.
//
// Math (identical to rounds 1-3, all PASSING):
//   K = [[pM+eI, G^T],[G, -F+eI]], pM = kron(M, I2), M = Minv^-1.
//   (pM+eI)^-1 = kron(W, I2), W = (I + e*Minv)^-1 Minv  (batch-shared).
//   Pair/row elimination leaves a symmetric 64x64 system in (lambda, delta):
//     A[r][c] = (w_r . w_c) * kap(r,c) - diag(e ... e, e/2 ... e/2)
//     kap(r,c) = W[i_r,i_c] - W[i_r,j_c] - W[j_r,i_c] + W[j_r,j_c]
//   rhs_r = (r normal ? min(dist*12.5, cor*Jcnv) : 0) - w_r.(q_j - q_i)
//   q = v - e*kron(W,I2) v ;  v_plus = q + kron(W,I2) y ; y = scatter(G^T l).
//
// Round-4 change: LU control structure = round-2's rolled 16-step chunks
// (small code, ~20 KB total vs ~40 KB full-unroll > 32 KB L1I) at round-3's
// fp32 precision (1 readlane per broadcast, 2-cyc fma issue). Inner column
// loop stays unrolled so row[] keeps static register indices; the broadcast
// lane k is a runtime SGPR (v_readlane supports SGPR lane select). Pivot
// column maintained in a register via a 16-wide capture window (stale-column
// updates are confined per-column and harmless — proven in round 2).
// v_rcp_f32 raw (1 ulp) instead of 1/x+Newton: error << bf16 compare floor.
//
// Known accounting (round-3 profile): ~58 us of dur_us is harness-side
// (268 MB d_ws re-poison fill ~40 us + restore/graph overhead) — immovable.

#define NBODY 64
#define NC    32
#define ND    128
#define EPS   1e-3f
#define WPAD  65

#define WAVE_SYNC() asm volatile("s_waitcnt lgkmcnt(0)" ::: "memory")

__device__ __forceinline__ float readlane_f(float x, int lane) {
  return __int_as_float(__builtin_amdgcn_readlane(__float_as_int(x), lane));
}

__device__ __forceinline__ float rcp_fast(float x) {
  float r;
  asm("v_rcp_f32 %0, %1" : "=v"(r) : "v"(x));
  return r;
}

// ---------------- Kernel 1: W = (I + eps*Minv)^-1 * Minv, Neumann ----------
__global__ __launch_bounds__(64) void precompute_W(
    const float* __restrict__ Minv, float* __restrict__ Wg) {
  const int lane = threadIdx.x;
  const int col = blockIdx.x;

  float Mr[NBODY];
  const float4* mv = (const float4*)(Minv + lane * NBODY);
#pragma unroll
  for (int e4 = 0; e4 < 16; ++e4) {
    float4 t = mv[e4];
    Mr[4 * e4] = t.x; Mr[4 * e4 + 1] = t.y;
    Mr[4 * e4 + 2] = t.z; Mr[4 * e4 + 3] = t.w;
  }

  const float dlt = (lane == col) ? 1.0f : 0.0f;
  float s = dlt;
#pragma unroll
  for (int t = 0; t < 6; ++t) {
    float a0 = 0.f, a1 = 0.f, a2 = 0.f, a3 = 0.f;
#pragma unroll
    for (int e = 0; e < NBODY; e += 4) {
      a0 = fmaf(Mr[e],     readlane_f(s, e),     a0);
      a1 = fmaf(Mr[e + 1], readlane_f(s, e + 1), a1);
      a2 = fmaf(Mr[e + 2], readlane_f(s, e + 2), a2);
      a3 = fmaf(Mr[e + 3], readlane_f(s, e + 3), a3);
    }
    s = dlt - EPS * ((a0 + a1) + (a2 + a3));
  }
  float a0 = 0.f, a1 = 0.f, a2 = 0.f, a3 = 0.f;
#pragma unroll
  for (int e = 0; e < NBODY; e += 4) {
    a0 = fmaf(Mr[e],     readlane_f(s, e),     a0);
    a1 = fmaf(Mr[e + 1], readlane_f(s, e + 1), a1);
    a2 = fmaf(Mr[e + 2], readlane_f(s, e + 2), a2);
    a3 = fmaf(Mr[e + 3], readlane_f(s, e + 3), a3);
  }
  Wg[lane * NBODY + col] = (a0 + a1) + (a2 + a3);
}

// ---------------- LU chunk: 16 rolled steps, static row[] indices ----------
template <int CS>
__device__ __forceinline__ void lu_chunk(float (&row)[64], float& rhs,
                                         float& pivcol, float& myinv,
                                         int lane) {
#pragma clang loop unroll(disable)
  for (int kk = 0; kk < 16; ++kk) {
    const int k = CS + kk;                    // runtime-uniform (SGPR)
    float pv = readlane_f(pivcol, k);
    float r0 = rcp_fast(pv);
    float m = (lane > k) ? pivcol * r0 : 0.0f;
    if (lane == k) myinv = r0;
    rhs = fmaf(-m, readlane_f(rhs, k), rhs);
#pragma unroll
    for (int c = CS; c < 64; ++c)             // static reg idx, dynamic lane
      row[c] = fmaf(-m, readlane_f(row[c], k), row[c]);
#pragma unroll
    for (int c = CS + 1; c < CS + 17 && c < 64; ++c)  // k+1 in window
      if (c == k + 1) pivcol = row[c];
  }
}

// ---------------- Kernel 2: wave-per-batch solve ----------------------------
__global__ __launch_bounds__(256, 1) void solve_batch(
    const float* __restrict__ x, const float* __restrict__ v,
    const int* __restrict__ cld, const float* __restrict__ dist,
    const float* __restrict__ cor, const float* __restrict__ Wg,
    float* __restrict__ out, int bs) {
  __shared__ float Wl[NBODY * WPAD];
  __shared__ float vL[4][ND];
  __shared__ float qL[4][ND];
  __shared__ float yL[4][ND];

  const int tid  = threadIdx.x;
  const int wave = tid >> 6;
  const int lane = tid & 63;
  const int b    = blockIdx.x * 4 + wave;

  for (int idx = tid; idx < NBODY * NBODY; idx += 256)
    Wl[(idx >> 6) * WPAD + (idx & 63)] = Wg[idx];
  __syncthreads();                    // the ONLY block-wide barrier
  if (b >= bs) return;

  const float* xb = x + b * ND;
  const float* vb = v + b * ND;
  float* vw = vL[wave];
  float* qw = qL[wave];
  float* yw = yL[wave];

  vw[lane]      = vb[lane];
  vw[lane + 64] = vb[lane + 64];

  // per-lane contact row: lanes 0..31 normal rows, 32..63 tangent rows
  const int rc = lane & 31;
  const int myi = cld[b * 2 * NC + 2 * rc];
  const int myj = cld[b * 2 * NC + 2 * rc + 1];
  float dx = xb[2 * myj]     - xb[2 * myi];
  float dy = xb[2 * myj + 1] - xb[2 * myi + 1];
  float il = 1.0f / sqrtf(dx * dx + dy * dy);
  float enx = dx * il, eny = dy * il;
  float wx = (lane < 32) ? enx : -eny;   // row weight vector (en or et)
  float wy = (lane < 32) ? eny : enx;
  WAVE_SYNC();                           // vw visible wave-wide

  // q = v - eps * kron(W,I2) v
  const int a1 = lane >> 1, kc = lane & 1;
  const float* W1 = Wl + a1 * WPAD;
  const float* W2 = Wl + (a1 + 32) * WPAD;
  {
    float s1 = 0.f, s2 = 0.f;
    for (int e = 0; e < NBODY; ++e) {
      float ve = vw[2 * e + kc];
      s1 = fmaf(W1[e], ve, s1);
      s2 = fmaf(W2[e], ve, s2);
    }
    qw[lane]      = vw[lane]      - EPS * s1;
    qw[lane + 64] = vw[lane + 64] - EPS * s2;
  }
  WAVE_SYNC();                           // qw visible wave-wide

  // rhs
  float rhs;
  {
    float qdx = qw[2 * myj]     - qw[2 * myi];
    float qdy = qw[2 * myj + 1] - qw[2 * myi + 1];
    float h = 0.0f;
    if (lane < 32) {
      float vdx = vw[2 * myj]     - vw[2 * myi];
      float vdy = vw[2 * myj + 1] - vw[2 * myi + 1];
      float jcnv = enx * vdx + eny * vdy;
      h = fminf(dist[b * NC + rc] * 12.5f, cor[b * NC + rc] * jcnv);
    }
    rhs = h - (wx * qdx + wy * qdy);
  }

  // assemble my row of S into registers (static c -> constant-lane readlane)
  float row[64];
  const float* Wi = Wl + myi * WPAD;
  const float* Wj = Wl + myj * WPAD;
#pragma unroll
  for (int c = 0; c < 64; ++c) {
    int ic = __builtin_amdgcn_readlane(myi, c);
    int jc = __builtin_amdgcn_readlane(myj, c);
    float wcx = readlane_f(wx, c);
    float wcy = readlane_f(wy, c);
    float kap = (Wi[ic] - Wi[jc]) - (Wj[ic] - Wj[jc]);
    float a = (wx * wcx + wy * wcy) * kap;
    if (c == lane) a -= (lane < 32) ? EPS : 0.5f * EPS;
    row[c] = a;
  }

  // LU, no pivoting (S = PSD - eps*diag, diag >= ~2; rounds 1-3 notes)
  float myinv = 0.0f;
  float pivcol = row[0];
  lu_chunk<0>(row, rhs, pivcol, myinv, lane);
  lu_chunk<16>(row, rhs, pivcol, myinv, lane);
  lu_chunk<32>(row, rhs, pivcol, myinv, lane);
  lu_chunk<48>(row, rhs, pivcol, myinv, lane);

  // back substitution (fully unrolled: row[c] needs static indices)
  float myx = 0.0f;
  float xacc = rhs;
#pragma unroll
  for (int c = 63; c >= 0; --c) {
    float xc = readlane_f(xacc, c) * readlane_f(myinv, c);
    if (lane == c) myx = xc;
    xacc = fmaf(-row[c], xc, xacc);
  }

  // y = G^T l scattered to particles (i_c in [0,32), j_c in [32,64))
  {
    float y1 = 0.f, y2 = 0.f;
    const int b1 = a1, b2 = a1 + 32;
#pragma unroll
    for (int c = 0; c < 32; ++c) {
      int ic = __builtin_amdgcn_readlane(myi, c);
      int jc = __builtin_amdgcn_readlane(myj, c);
      float ex = readlane_f(wx, c),      ey = readlane_f(wy, c);       // en
      float tx = readlane_f(wx, c + 32), ty = readlane_f(wy, c + 32);  // et
      float lam = readlane_f(myx, c);
      float del = readlane_f(myx, c + 32);
      float wk = (kc ? ey : ex) * lam + (kc ? ty : tx) * del;
      y1 -= (ic == b1) ? wk : 0.0f;
      y2 += (jc == b2) ? wk : 0.0f;
    }
    yw[lane]      = y1;
    yw[lane + 64] = y2;
  }
  WAVE_SYNC();                           // yw visible wave-wide

  // v_plus = q + kron(W,I2) y ; out = [x passthrough, v_plus]
  {
    float s1 = 0.f, s2 = 0.f;
    for (int e = 0; e < NBODY; ++e) {
      float ye = yw[2 * e + kc];
      s1 = fmaf(W1[e], ye, s1);
      s2 = fmaf(W2[e], ye, s2);
    }
    float* ob = out + b * 256;
    ob[lane]       = xb[lane];
    ob[lane + 64]  = xb[lane + 64];
    ob[128 + lane] = qw[lane] + s1;
    ob[192 + lane] = qw[lane + 64] + s2;
  }
}

extern "C" void kernel_launch(void* const* d_in, const int* in_sizes, int n_in,
                              void* d_out, int out_size, void* d_ws, size_t ws_size,
                              hipStream_t stream) {
  const float* x    = (const float*)d_in[0];
  const float* v    = (const float*)d_in[1];
  const int*   cld  = (const int*)  d_in[2];
  const float* dist = (const float*)d_in[3];
  // d_in[4] = mu: drops out of the output (eliminated multipliers only)
  const float* cor  = (const float*)d_in[5];
  const float* Minv = (const float*)d_in[6];
  float* out = (float*)d_out;

  const int bs = in_sizes[0] / ND;          // 1024
  float* W = (float*)d_ws;                  // 64*64*4 = 16 KB scratch

  precompute_W<<<NBODY, 64, 0, stream>>>(Minv, W);
  solve_batch<<<(bs + 3) / 4, 256, 0, stream>>>(x, v, cld, dist, cor, W, out, bs);
}

// Round 5
// 95.017 us; speedup vs baseline: 1.0671x; 1.0671x over previous
//
#include <hip/hip_runtime.h>
#include <math.h>

// ImpulseSolverLCP — 2-waves-per-batch Gauss-Jordan, fp32.
//
// Math (identical to rounds 1-4, all PASSING):
//   K = [[pM+eI, G^T],[G, -F+eI]], pM = kron(M, I2), M = Minv^-1.
//   (pM+eI)^-1 = kron(W, I2), W = (I + e*Minv)^-1 Minv  (batch-shared).
//   Pair/row elimination leaves a symmetric 64x64 system in (lambda, delta):
//     A[r][c] = (w_r . w_c) * kap(r,c) - diag(e..e, e/2..e/2)
//     kap(r,c) = W[i_r,i_c] - W[i_r,j_c] - W[j_r,i_c] + W[j_r,j_c]
//   rhs_r = (r normal ? min(dist*12.5, cor*Jcnv) : 0) - w_r.(q_j - q_i)
//   q = v - e*kron(W,I2) v ;  v_plus = q + kron(W,I2) y ; y = scatter(G^T l).
//
// Round-5 structure change (why): solve_batch was ~36us at ~50% VALUBusy with
// 1 wave/SIMD (1024 waves on 1024 SIMDs) — half stalls, unfillable. Now:
//  * 2 waves per batch, column-interleaved (wave wp owns cols c%2==wp,
//    rowh[32]/lane) -> 2048 waves = 2/SIMD: per-wave instrs halve AND the
//    co-resident wave fills stall bubbles.
//  * Gauss-Jordan, not LU: update ALL rows each step (mask lane==k only —
//    free in a wave-wide fma) => identical pivot sequence, same cost as the
//    triangular update, and NO 64-step serial back-substitution:
//    x[lane] = rhs[lane]*dinv[lane].
//  * Per step, only the owner computes m = A[.][k]*rcp(A[k][k]) and
//    publishes it in a parity-double-buffered LDS slot; ONE barrier/step.
//    Buffer safety: reads of buf[p] at step k happen between barrier(k) and
//    barrier(k+1); the next write to buf[p] (step k+2) is after barrier(k+1).
//  * rhs maintained redundantly (bitwise-identically) by both waves, so the
//    solution is lane-distributed in both waves and q/y/out phases split
//    into per-wave component halves (t = lane + 64*wp).
//  * Uniform inner start tt=k>>1: the owner touches col k (harmless: never
//    read again; lane k masked) and for odd k the non-owner touches dead
//    col k-1 (adds m*(elimination residual ~0) to a never-read column).

#define NBODY 64
#define NC    32
#define ND    128
#define EPS   1e-3f
#define WPAD  65

__device__ __forceinline__ float readlane_f(float x, int lane) {
  return __int_as_float(__builtin_amdgcn_readlane(__float_as_int(x), lane));
}

__device__ __forceinline__ float rcp_fast(float x) {
  float r;
  asm("v_rcp_f32 %0, %1" : "=v"(r) : "v"(x));
  return r;
}

// ---------------- Kernel 1: W = (I + eps*Minv)^-1 * Minv, Neumann ----------
__global__ __launch_bounds__(64) void precompute_W(
    const float* __restrict__ Minv, float* __restrict__ Wg) {
  const int lane = threadIdx.x;
  const int col = blockIdx.x;

  float Mr[NBODY];
  const float4* mv = (const float4*)(Minv + lane * NBODY);
#pragma unroll
  for (int e4 = 0; e4 < 16; ++e4) {
    float4 t = mv[e4];
    Mr[4 * e4] = t.x; Mr[4 * e4 + 1] = t.y;
    Mr[4 * e4 + 2] = t.z; Mr[4 * e4 + 3] = t.w;
  }

  const float dlt = (lane == col) ? 1.0f : 0.0f;
  float s = dlt;
#pragma unroll
  for (int t = 0; t < 6; ++t) {
    float a0 = 0.f, a1 = 0.f, a2 = 0.f, a3 = 0.f;
#pragma unroll
    for (int e = 0; e < NBODY; e += 4) {
      a0 = fmaf(Mr[e],     readlane_f(s, e),     a0);
      a1 = fmaf(Mr[e + 1], readlane_f(s, e + 1), a1);
      a2 = fmaf(Mr[e + 2], readlane_f(s, e + 2), a2);
      a3 = fmaf(Mr[e + 3], readlane_f(s, e + 3), a3);
    }
    s = dlt - EPS * ((a0 + a1) + (a2 + a3));
  }
  float a0 = 0.f, a1 = 0.f, a2 = 0.f, a3 = 0.f;
#pragma unroll
  for (int e = 0; e < NBODY; e += 4) {
    a0 = fmaf(Mr[e],     readlane_f(s, e),     a0);
    a1 = fmaf(Mr[e + 1], readlane_f(s, e + 1), a1);
    a2 = fmaf(Mr[e + 2], readlane_f(s, e + 2), a2);
    a3 = fmaf(Mr[e + 3], readlane_f(s, e + 3), a3);
  }
  Wg[lane * NBODY + col] = (a0 + a1) + (a2 + a3);
}

// ---------------- Kernel 2: 2-wave-per-batch Gauss-Jordan solve -------------
__global__ __launch_bounds__(256, 2) void solve_batch(
    const float* __restrict__ x, const float* __restrict__ v,
    const int* __restrict__ cld, const float* __restrict__ dist,
    const float* __restrict__ cor, const float* __restrict__ Wg,
    float* __restrict__ out) {
  __shared__ float Wl[NBODY * WPAD];
  __shared__ float vw_[2][ND];
  __shared__ float qw_[2][ND];
  __shared__ float yw_[2][ND];
  __shared__ float mb_[2][2][64];   // [pair][step parity][lane]
  __shared__ float dv_[2][64];      // diag inverses

  const int tid  = threadIdx.x;
  const int wave = tid >> 6;
  const int lane = tid & 63;
  const int pair = wave >> 1;       // batch slot within block (0,1)
  const int wp   = wave & 1;        // column parity owned by this wave
  const int b    = blockIdx.x * 2 + pair;   // grid sized exactly: bs even

  for (int idx = tid; idx < NBODY * NBODY; idx += 256)
    Wl[(idx >> 6) * WPAD + (idx & 63)] = Wg[idx];

  const float* xb = x + b * ND;
  const float* vb = v + b * ND;
  float* vw = vw_[pair];
  float* qw = qw_[pair];
  float* yw = yw_[pair];
  float* mb0 = mb_[pair][0];
  float* mb1 = mb_[pair][1];
  float* dv = dv_[pair];

  const int t = lane + 64 * wp;     // this wave's output-component half
  vw[t] = vb[t];

  // per-lane contact/row data (bitwise identical in both waves of the pair)
  const int rc = lane & 31;
  const int myi = cld[b * 2 * NC + 2 * rc];
  const int myj = cld[b * 2 * NC + 2 * rc + 1];
  float dx = xb[2 * myj]     - xb[2 * myi];
  float dy = xb[2 * myj + 1] - xb[2 * myi + 1];
  float il = 1.0f / sqrtf(dx * dx + dy * dy);
  float enx = dx * il, eny = dy * il;
  float wx = (lane < 32) ? enx : -eny;   // row weight vector (en or et)
  float wy = (lane < 32) ? eny : enx;
  __syncthreads();                       // Wl + vw visible

  // q half: q = v - eps*kron(W,I2) v, component t
  const int kc = lane & 1;
  const int a  = t >> 1;
  const float* Wa = Wl + a * WPAD;
  {
    float s = 0.f;
    for (int e = 0; e < NBODY; ++e) s = fmaf(Wa[e], vw[2 * e + kc], s);
    qw[t] = vw[t] - EPS * s;
  }
  __syncthreads();                       // qw visible

  // rhs (computed identically by both waves)
  float rhs;
  {
    float qdx = qw[2 * myj]     - qw[2 * myi];
    float qdy = qw[2 * myj + 1] - qw[2 * myi + 1];
    float h = 0.0f;
    if (lane < 32) {
      float vdx = vw[2 * myj]     - vw[2 * myi];
      float vdy = vw[2 * myj + 1] - vw[2 * myi + 1];
      float jcnv = enx * vdx + eny * vdy;
      h = fminf(dist[b * NC + rc] * 12.5f, cor[b * NC + rc] * jcnv);
    }
    rhs = h - (wx * qdx + wy * qdy);
  }

  // assemble my 32 columns c = 2*tt + wp of row `lane`
  float rowh[32];
  const float* Wi = Wl + myi * WPAD;
  const float* Wj = Wl + myj * WPAD;
#pragma unroll
  for (int tt = 0; tt < 32; ++tt) {
    int c = 2 * tt + wp;                       // runtime-uniform (SGPR)
    int ic = __builtin_amdgcn_readlane(myi, c);
    int jc = __builtin_amdgcn_readlane(myj, c);
    float wcx = readlane_f(wx, c);
    float wcy = readlane_f(wy, c);
    float kap = (Wi[ic] - Wi[jc]) - (Wj[ic] - Wj[jc]);
    float aa = (wx * wcx + wy * wcy) * kap;
    aa = (c == lane) ? aa - ((lane < 32) ? EPS : 0.5f * EPS) : aa;
    rowh[tt] = aa;
  }

  // Gauss-Jordan, no pivoting (S = PSD - eps*diag, diag >= ~2; round-1 notes)
#pragma unroll
  for (int k = 0; k < 64; ++k) {
    const int ow = k & 1;                      // owner wave parity (literal)
    float m;
    if (wp == ow) {                            // wave-uniform branch
      float pv = readlane_f(rowh[k >> 1], k);  // static reg idx, const lane
      float r0 = rcp_fast(pv);
      m = (lane == k) ? 0.0f : rowh[k >> 1] * r0;
      (ow ? mb1 : mb0)[lane] = m;
      if (lane == k) dv[k] = r0;
    }
    __syncthreads();
    if (wp != ow) m = (ow ? mb1 : mb0)[lane];
    rhs = fmaf(-m, readlane_f(rhs, k), rhs);
#pragma unroll
    for (int tt = (k >> 1); tt < 32; ++tt)     // uniform start; see header
      rowh[tt] = fmaf(-m, readlane_f(rowh[tt], k), rowh[tt]);
  }

  // solution, lane-distributed, identical in both waves
  // (dv[k] written before barrier(k) -> visible; A now diagonal)
  float myx = rhs * dv[lane];

  // y = G^T l, this wave's component half (i_c in [0,32), j_c in [32,64))
  {
    float y = 0.f;
#pragma unroll
    for (int c = 0; c < 32; ++c) {
      float ex = readlane_f(wx, c),      ey = readlane_f(wy, c);       // en
      float tx = readlane_f(wx, c + 32), ty = readlane_f(wy, c + 32);  // et
      float lam = readlane_f(myx, c);
      float del = readlane_f(myx, c + 32);
      float wk = (kc ? ey : ex) * lam + (kc ? ty : tx) * del;
      if (wp == 0) {
        int ic = __builtin_amdgcn_readlane(myi, c);
        y -= (ic == a) ? wk : 0.0f;
      } else {
        int jc = __builtin_amdgcn_readlane(myj, c);
        y += (jc == a) ? wk : 0.0f;
      }
    }
    yw[t] = y;
  }
  __syncthreads();                       // yw visible

  // v_plus = q + kron(W,I2) y ; out = [x passthrough, v_plus], half per wave
  {
    float s = 0.f;
    for (int e = 0; e < NBODY; ++e) s = fmaf(Wa[e], yw[2 * e + kc], s);
    float* ob = out + b * 256;
    ob[t]       = xb[t];
    ob[128 + t] = qw[t] + s;
  }
}

extern "C" void kernel_launch(void* const* d_in, const int* in_sizes, int n_in,
                              void* d_out, int out_size, void* d_ws, size_t ws_size,
                              hipStream_t stream) {
  const float* x    = (const float*)d_in[0];
  const float* v    = (const float*)d_in[1];
  const int*   cld  = (const int*)  d_in[2];
  const float* dist = (const float*)d_in[3];
  // d_in[4] = mu: drops out of the output (eliminated multipliers only)
  const float* cor  = (const float*)d_in[5];
  const float* Minv = (const float*)d_in[6];
  float* out = (float*)d_out;

  const int bs = in_sizes[0] / ND;          // 1024 (even)
  float* W = (float*)d_ws;                  // 64*64*4 = 16 KB scratch

  precompute_W<<<NBODY, 64, 0, stream>>>(Minv, W);
  solve_batch<<<bs / 2, 256, 0, stream>>>(x, v, cld, dist, cor, W, out);
}

// Round 6
// 93.372 us; speedup vs baseline: 1.0859x; 1.0176x over previous
//
#include <hip/hip_runtime.h>
#include <math.h>

// ImpulseSolverLCP — 4-waves-per-batch Gauss-Jordan, fp32, 4-pivot phases.
//
// Math (identical to rounds 1-5, all PASSING):
//   K = [[pM+eI, G^T],[G, -F+eI]], pM = kron(M, I2), M = Minv^-1.
//   (pM+eI)^-1 = kron(W, I2), W = (I + e*Minv)^-1 Minv  (batch-shared).
//   Pair/row elimination leaves a symmetric 64x64 system in (lambda, delta):
//     A[r][c] = (w_r . w_c) * kap(r,c) - diag(e..e, e/2..e/2)
//     kap(r,c) = W[i_r,i_c] - W[i_r,j_c] - W[j_r,i_c] + W[j_r,j_c]
//   rhs_r = (r normal ? min(dist*12.5, cor*Jcnv) : 0) - w_r.(q_j - q_i)
//   q = v - e*kron(W,I2) v ;  v_plus = q + kron(W,I2) y ; y = scatter(G^T l).
//
// Round-6 structure (why): round-5 solve was stall-bound — 64 barriers (one
// per pivot), each with an LDS round-trip (~120cyc) on the critical path, at
// only 2 waves/SIMD. Now:
//  * 1 block (4 waves) per batch -> 4096 waves = 4/SIMD = real cross-batch
//    TLP on every SIMD (4 blocks/CU, 20 KB LDS, VGPR ~70).
//  * Columns owned in interleaved 4-col chunks: wave w owns global chunks
//    h%4==w (h=c>>2), local col q -> c = 16*(q>>2) + 4*w + (q&3).
//  * 16 phases of 4 pivots: owner does 4 SERIAL pivots in its own chunk
//    (static reg indices), publishes float4 m-vector per lane in a
//    parity-double-buffered LDS slot; ONE barrier per phase (64 -> 16).
//    Buffer safety: phase g readers finish before barrier(g+1); the next
//    writer of buffer g&1 (phase g+2's owner) starts after barrier(g+1).
//  * rhs maintained redundantly (bitwise-identically) by all 4 waves ->
//    solution is lane-distributed everywhere; dv (pivot reciprocals) via LDS.
//  * Waves 2,3 s_endpgm after phase 15 (HW decrements the barrier count);
//    waves 0,1 do the y-scatter + final matvec component halves.
// Elimination arithmetic per (row,col,k) identical to round 5 -> same
// numerics (absmax ~0.0247 << 8.9e-2 threshold).

#define NBODY 64
#define NC    32
#define ND    128
#define EPS   1e-3f
#define WPAD  65

__device__ __forceinline__ float readlane_f(float x, int lane) {
  return __int_as_float(__builtin_amdgcn_readlane(__float_as_int(x), lane));
}

__device__ __forceinline__ float rcp_fast(float x) {
  float r;
  asm("v_rcp_f32 %0, %1" : "=v"(r) : "v"(x));
  return r;
}

// ---------------- Kernel 1: W = (I + eps*Minv)^-1 * Minv, Neumann ----------
__global__ __launch_bounds__(64) void precompute_W(
    const float* __restrict__ Minv, float* __restrict__ Wg) {
  const int lane = threadIdx.x;
  const int col = blockIdx.x;

  float Mr[NBODY];
  const float4* mv = (const float4*)(Minv + lane * NBODY);
#pragma unroll
  for (int e4 = 0; e4 < 16; ++e4) {
    float4 t = mv[e4];
    Mr[4 * e4] = t.x; Mr[4 * e4 + 1] = t.y;
    Mr[4 * e4 + 2] = t.z; Mr[4 * e4 + 3] = t.w;
  }

  const float dlt = (lane == col) ? 1.0f : 0.0f;
  float s = dlt;
#pragma unroll
  for (int t = 0; t < 6; ++t) {
    float a0 = 0.f, a1 = 0.f, a2 = 0.f, a3 = 0.f;
#pragma unroll
    for (int e = 0; e < NBODY; e += 4) {
      a0 = fmaf(Mr[e],     readlane_f(s, e),     a0);
      a1 = fmaf(Mr[e + 1], readlane_f(s, e + 1), a1);
      a2 = fmaf(Mr[e + 2], readlane_f(s, e + 2), a2);
      a3 = fmaf(Mr[e + 3], readlane_f(s, e + 3), a3);
    }
    s = dlt - EPS * ((a0 + a1) + (a2 + a3));
  }
  float a0 = 0.f, a1 = 0.f, a2 = 0.f, a3 = 0.f;
#pragma unroll
  for (int e = 0; e < NBODY; e += 4) {
    a0 = fmaf(Mr[e],     readlane_f(s, e),     a0);
    a1 = fmaf(Mr[e + 1], readlane_f(s, e + 1), a1);
    a2 = fmaf(Mr[e + 2], readlane_f(s, e + 2), a2);
    a3 = fmaf(Mr[e + 3], readlane_f(s, e + 3), a3);
  }
  Wg[lane * NBODY + col] = (a0 + a1) + (a2 + a3);
}

// ---------------- Kernel 2: 4-wave-per-batch Gauss-Jordan solve -------------
__global__ __launch_bounds__(256, 4) void solve_batch(
    const float* __restrict__ x, const float* __restrict__ v,
    const int* __restrict__ cld, const float* __restrict__ dist,
    const float* __restrict__ cor, const float* __restrict__ Wg,
    float* __restrict__ out) {
  __shared__ float Wl[NBODY * WPAD];
  __shared__ float vw[ND], qw[ND], yw[ND];
  __shared__ float4 mrow[2][64];     // [phase parity][lane] = (m0,m1,m2,m3)
  __shared__ float dv[64];           // pivot reciprocals

  const int tid  = threadIdx.x;
  const int w    = tid >> 6;         // wave id 0..3 (uniform per wave)
  const int lane = tid & 63;
  const int b    = blockIdx.x;

  for (int idx = tid; idx < NBODY * NBODY; idx += 256)
    Wl[(idx >> 6) * WPAD + (idx & 63)] = Wg[idx];

  const float* xb = x + b * ND;
  const float* vb = v + b * ND;

  const int half = w & 1;
  const int t = lane + 64 * half;    // output component (waves 0,1)
  if (w < 2) vw[t] = vb[t];

  // per-lane contact/row data (identical in all 4 waves)
  const int rc = lane & 31;
  const int myi = cld[b * 2 * NC + 2 * rc];
  const int myj = cld[b * 2 * NC + 2 * rc + 1];
  float dx = xb[2 * myj]     - xb[2 * myi];
  float dy = xb[2 * myj + 1] - xb[2 * myi + 1];
  float il = 1.0f / sqrtf(dx * dx + dy * dy);
  float enx = dx * il, eny = dy * il;
  float wx = (lane < 32) ? enx : -eny;   // row weight vector (en or et)
  float wy = (lane < 32) ? eny : enx;

  __syncthreads();                       // #1: Wl + vw visible

  const int kc = lane & 1;
  const int a  = t >> 1;
  const float* Wa = Wl + a * WPAD;
  if (w < 2) {                           // q = v - eps*kron(W,I2) v, half each
    float s = 0.f;
    for (int e = 0; e < NBODY; ++e) s = fmaf(Wa[e], vw[2 * e + kc], s);
    qw[t] = vw[t] - EPS * s;
  }

  // assemble my 16 columns (overlaps waves 0,1's q-matvec)
  float rowq[16];
  const float* Wi = Wl + myi * WPAD;
  const float* Wj = Wl + myj * WPAD;
#pragma unroll
  for (int q = 0; q < 16; ++q) {
    int c = 16 * (q >> 2) + 4 * w + (q & 3);   // runtime-uniform (SGPR)
    int ic = __builtin_amdgcn_readlane(myi, c);
    int jc = __builtin_amdgcn_readlane(myj, c);
    float wcx = readlane_f(wx, c);
    float wcy = readlane_f(wy, c);
    float kap = (Wi[ic] - Wi[jc]) - (Wj[ic] - Wj[jc]);
    float aa = (wx * wcx + wy * wcy) * kap;
    aa = (c == lane) ? aa - ((lane < 32) ? EPS : 0.5f * EPS) : aa;
    rowq[q] = aa;
  }

  __syncthreads();                       // #2: qw visible

  // rhs (computed identically by all 4 waves)
  float rhs;
  {
    float qdx = qw[2 * myj]     - qw[2 * myi];
    float qdy = qw[2 * myj + 1] - qw[2 * myi + 1];
    float h = 0.0f;
    if (lane < 32) {
      float vdx = vw[2 * myj]     - vw[2 * myi];
      float vdy = vw[2 * myj + 1] - vw[2 * myi + 1];
      float jcnv = enx * vdx + eny * vdy;
      h = fminf(dist[b * NC + rc] * 12.5f, cor[b * NC + rc] * jcnv);
    }
    rhs = h - (wx * qdx + wy * qdy);
  }

  // Gauss-Jordan, no pivoting (S = PSD - eps*diag, diag >= ~2; round-1 notes)
  // 16 phases x 4 pivots; one barrier per phase.
#pragma unroll
  for (int g = 0; g < 16; ++g) {
    const int om = g & 3;                // owner wave (compile-time)
    const int gc = g >> 2;               // owner's local chunk
    float m0, m1, m2, m3;
    if (w == om) {                       // wave-uniform branch
      const int base = 4 * gc;
      {  // pivot 4g+0
        const int k = 4 * g;
        float r = rcp_fast(readlane_f(rowq[base], k));
        if (lane == k) dv[k] = r;
        m0 = (lane == k) ? 0.f : rowq[base] * r;
        rowq[base+1] = fmaf(-m0, readlane_f(rowq[base+1], k), rowq[base+1]);
        rowq[base+2] = fmaf(-m0, readlane_f(rowq[base+2], k), rowq[base+2]);
        rowq[base+3] = fmaf(-m0, readlane_f(rowq[base+3], k), rowq[base+3]);
      }
      {  // pivot 4g+1
        const int k = 4 * g + 1;
        float r = rcp_fast(readlane_f(rowq[base+1], k));
        if (lane == k) dv[k] = r;
        m1 = (lane == k) ? 0.f : rowq[base+1] * r;
        rowq[base+2] = fmaf(-m1, readlane_f(rowq[base+2], k), rowq[base+2]);
        rowq[base+3] = fmaf(-m1, readlane_f(rowq[base+3], k), rowq[base+3]);
      }
      {  // pivot 4g+2
        const int k = 4 * g + 2;
        float r = rcp_fast(readlane_f(rowq[base+2], k));
        if (lane == k) dv[k] = r;
        m2 = (lane == k) ? 0.f : rowq[base+2] * r;
        rowq[base+3] = fmaf(-m2, readlane_f(rowq[base+3], k), rowq[base+3]);
      }
      {  // pivot 4g+3
        const int k = 4 * g + 3;
        float r = rcp_fast(readlane_f(rowq[base+3], k));
        if (lane == k) dv[k] = r;
        m3 = (lane == k) ? 0.f : rowq[base+3] * r;
      }
      mrow[g & 1][lane] = make_float4(m0, m1, m2, m3);
    }
    __syncthreads();                     // m-vector (+dv) published
    if (w != om) {
      float4 mv = mrow[g & 1][lane];
      m0 = mv.x; m1 = mv.y; m2 = mv.z; m3 = mv.w;
    }
    // rhs: 4 sequential eliminations (lane 4g+s updated before broadcast s)
    rhs = fmaf(-m0, readlane_f(rhs, 4 * g),     rhs);
    rhs = fmaf(-m1, readlane_f(rhs, 4 * g + 1), rhs);
    rhs = fmaf(-m2, readlane_f(rhs, 4 * g + 2), rhs);
    rhs = fmaf(-m3, readlane_f(rhs, 4 * g + 3), rhs);
    // apply to my remaining columns (c > 4g+3)
#pragma unroll
    for (int cl = 0; cl < 4; ++cl) {
      if (cl < gc) continue;                       // compile-time prune
      if ((cl > gc) || (w > om)) {                 // uniform scalar guard
#pragma unroll
        for (int within = 0; within < 4; ++within) {
          const int q = 4 * cl + within;
          rowq[q] = fmaf(-m0, readlane_f(rowq[q], 4 * g),     rowq[q]);
          rowq[q] = fmaf(-m1, readlane_f(rowq[q], 4 * g + 1), rowq[q]);
          rowq[q] = fmaf(-m2, readlane_f(rowq[q], 4 * g + 2), rowq[q]);
          rowq[q] = fmaf(-m3, readlane_f(rowq[q], 4 * g + 3), rowq[q]);
        }
      }
    }
  }

  if (w >= 2) return;   // waves 2,3 done (HW decrements barrier wave count)

  // solution, lane-distributed (dv fully written before phase barriers)
  float myx = rhs * dv[lane];

  // y = G^T l, component half per wave (i in [0,32), j in [32,64))
  {
    float y = 0.f;
#pragma unroll
    for (int c = 0; c < NC; ++c) {
      float ex = readlane_f(wx, c),      ey = readlane_f(wy, c);       // en
      float tx = readlane_f(wx, c + 32), ty = readlane_f(wy, c + 32);  // et
      float lam = readlane_f(myx, c);
      float del = readlane_f(myx, c + 32);
      float wk = (kc ? ey : ex) * lam + (kc ? ty : tx) * del;
      if (w == 0) {
        int ic = __builtin_amdgcn_readlane(myi, c);
        y -= (ic == a) ? wk : 0.0f;
      } else {
        int jc = __builtin_amdgcn_readlane(myj, c);
        y += (jc == a) ? wk : 0.0f;
      }
    }
    yw[t] = y;
  }
  __syncthreads();                       // #3: yw visible (waves 0,1 alive)

  // v_plus = q + kron(W,I2) y ; out = [x passthrough, v_plus], half per wave
  {
    float s = 0.f;
    for (int e = 0; e < NBODY; ++e) s = fmaf(Wa[e], yw[2 * e + kc], s);
    float* ob = out + b * 256;
    ob[t]       = xb[t];
    ob[128 + t] = qw[t] + s;
  }
}

extern "C" void kernel_launch(void* const* d_in, const int* in_sizes, int n_in,
                              void* d_out, int out_size, void* d_ws, size_t ws_size,
                              hipStream_t stream) {
  const float* x    = (const float*)d_in[0];
  const float* v    = (const float*)d_in[1];
  const int*   cld  = (const int*)  d_in[2];
  const float* dist = (const float*)d_in[3];
  // d_in[4] = mu: drops out of the output (eliminated multipliers only)
  const float* cor  = (const float*)d_in[5];
  const float* Minv = (const float*)d_in[6];
  float* out = (float*)d_out;

  const int bs = in_sizes[0] / ND;          // 1024
  float* W = (float*)d_ws;                  // 64*64*4 = 16 KB scratch

  precompute_W<<<NBODY, 64, 0, stream>>>(Minv, W);
  solve_batch<<<bs, 256, 0, stream>>>(x, v, cld, dist, cor, W, out);
}